// Round 1
// baseline (1316.407 us; speedup 1.0000x reference)
//
#include <hip/hip_runtime.h>
#include <hip/hip_bf16.h>

// Problem dims (fixed by reference setup_inputs)
constexpr int Bn = 4, Cc = 32, Hh = 256, Ww = 256;
constexpr int H2 = 128, W2 = 128;      // half-res
constexpr int NF = 128;                // KAN feature dim (= W2)
constexpr long NROWS = (long)Bn * Cc * 4 * H2;  // 65536 KAN rows

// ---- cubic B-spline bases, matching the reference Cox-de Boor recursion ----
// grid[t] = (t-3)*0.4f - 1.0f  (t = 0..11), computed exactly as jnp does.
__device__ __forceinline__ float gridv(int t) {
    return (float)(t - 3) * 0.4f - 1.0f;
}

__device__ __forceinline__ void spline_bases(float x, float B[8]) {
    float b0[11];
#pragma unroll
    for (int t = 0; t < 11; ++t) {
        b0[t] = (x >= gridv(t) && x < gridv(t + 1)) ? 1.0f : 0.0f;
    }
    float b1[10];
#pragma unroll
    for (int t = 0; t < 10; ++t) {
        float d0 = gridv(t + 1) - gridv(t);
        float d1 = gridv(t + 2) - gridv(t + 1);
        b1[t] = (x - gridv(t)) * (1.0f / d0) * b0[t]
              + (gridv(t + 2) - x) * (1.0f / d1) * b0[t + 1];
    }
    float b2[9];
#pragma unroll
    for (int t = 0; t < 9; ++t) {
        float d0 = gridv(t + 2) - gridv(t);
        float d1 = gridv(t + 3) - gridv(t + 1);
        b2[t] = (x - gridv(t)) * (1.0f / d0) * b1[t]
              + (gridv(t + 3) - x) * (1.0f / d1) * b1[t + 1];
    }
#pragma unroll
    for (int t = 0; t < 8; ++t) {
        float d0 = gridv(t + 3) - gridv(t);
        float d1 = gridv(t + 4) - gridv(t + 1);
        B[t] = (x - gridv(t)) * (1.0f / d0) * b2[t]
             + (gridv(t + 4) - x) * (1.0f / d1) * b2[t + 1];
    }
}

// ---- K1: Haar forward. wt rows n=((b*C+c)*4+k)*H2+i, feature dim j ----
__global__ __launch_bounds__(256) void k_haar(const float* __restrict__ x,
                                              float* __restrict__ wt) {
    int idx = blockIdx.x * 256 + threadIdx.x;     // (b,c,i,j)
    int j = idx & 127;
    int tmp = idx >> 7;
    int i = tmp & 127; tmp >>= 7;
    int c = tmp & 31;  int b = tmp >> 5;

    const float* base = x + (((long)(b * Cc + c) * Hh + 2 * i) * Ww);
    float2 r0 = ((const float2*)base)[j];
    float2 r1 = ((const float2*)(base + Ww))[j];
    float a = r0.x, bb = r0.y, cc = r1.x, dd = r1.y;

    float k0 = 0.5f * (a + bb + cc + dd);
    float k1 = 0.5f * (a + bb - cc - dd);
    float k2 = 0.5f * (a - bb + cc - dd);
    float k3 = 0.5f * (a - bb - cc + dd);

    long plane = (long)H2 * W2;                    // stride between k planes
    long nbase = (((long)(b * Cc + c) * 4) * H2 + i) * (long)W2 + j;
    wt[nbase]             = k0;
    wt[nbase + plane]     = k1;
    wt[nbase + 2 * plane] = k2;
    wt[nbase + 3 * plane] = k3;
}

// ---- K2: depthwise 5x5 conv (cross-correlation) + bias -> d_out (skip) ----
__global__ __launch_bounds__(256) void k_conv(const float* __restrict__ x,
                                              const float* __restrict__ w,
                                              const float* __restrict__ bias,
                                              float* __restrict__ out) {
    int idx = blockIdx.x * 256 + threadIdx.x;      // (b,c,y,xc)
    int xc = idx & 255;
    int tmp = idx >> 8;
    int y = tmp & 255; tmp >>= 8;
    int c = tmp & 31;  int b = tmp >> 5;

    const float* xp = x + (long)(b * Cc + c) * Hh * Ww;
    const float* wp = w + c * 25;
    float acc = bias[c];
#pragma unroll
    for (int ky = 0; ky < 5; ++ky) {
        int yy = y + ky - 2;
        if (yy < 0 || yy >= Hh) continue;
#pragma unroll
        for (int kx = 0; kx < 5; ++kx) {
            int xx = xc + kx - 2;
            if (xx < 0 || xx >= Ww) continue;
            acc += xp[yy * Ww + xx] * wp[ky * 5 + kx];
        }
    }
    out[idx] = acc;
}

// ---- K3: KAN linear, in-place on wt buffer (rows fully staged in LDS) ----
constexpr int KROWS = 16;
__global__ __launch_bounds__(256) void k_kan(float* __restrict__ wtz,
                                             const float* __restrict__ base_w,
                                             const float* __restrict__ spline_w,
                                             const float* __restrict__ scaler) {
    __shared__ float s_silu[KROWS][NF];        // 8 KB
    __shared__ float s_b[KROWS][NF][8];        // 64 KB
    int t = threadIdx.x;
    long n0 = (long)blockIdx.x * KROWS;

    // load + transform 16 rows (2048 elements, 8 per thread)
#pragma unroll
    for (int e = 0; e < 8; ++e) {
        int idx = t + e * 256;
        int r = idx >> 7, i = idx & 127;
        float xv = wtz[(n0 + r) * NF + i];
        s_silu[r][i] = xv / (1.0f + expf(-xv));   // silu
        float B[8];
        spline_bases(xv, B);
#pragma unroll
        for (int g = 0; g < 8; ++g) s_b[r][i][g] = B[g];
    }
    __syncthreads();

    int o = t & 127;
    int half = t >> 7;                // rows half*8 .. half*8+7
    float acc[8];
#pragma unroll
    for (int r = 0; r < 8; ++r) acc[r] = 0.0f;

    for (int i = 0; i < NF; ++i) {
        float bw = base_w[o * NF + i];
        float sc = scaler[o * NF + i];
        const float4* swp = (const float4*)(spline_w + ((long)(o * NF + i)) * 8);
        float4 w0 = swp[0], w1 = swp[1];
#pragma unroll
        for (int r = 0; r < 8; ++r) {
            int rr = half * 8 + r;
            const float* bp = s_b[rr][i];
            float sp = bp[0] * w0.x + bp[1] * w0.y + bp[2] * w0.z + bp[3] * w0.w
                     + bp[4] * w1.x + bp[5] * w1.y + bp[6] * w1.z + bp[7] * w1.w;
            acc[r] += s_silu[rr][i] * bw + sc * sp;
        }
    }

    // all global reads of these rows happened before the sync; safe in-place
#pragma unroll
    for (int r = 0; r < 8; ++r) {
        wtz[(n0 + half * 8 + r) * NF + o] = acc[r];
    }
}

// ---- K4: inverse Haar, add into d_out (which holds skip) ----
__global__ __launch_bounds__(256) void k_inv(const float* __restrict__ z,
                                             float* __restrict__ out) {
    int idx = blockIdx.x * 256 + threadIdx.x;     // (b,c,i,j)
    int j = idx & 127;
    int tmp = idx >> 7;
    int i = tmp & 127; tmp >>= 7;
    int c = tmp & 31;  int b = tmp >> 5;

    long plane = (long)H2 * W2;
    long nbase = (((long)(b * Cc + c) * 4) * H2 + i) * (long)W2 + j;
    float z0 = z[nbase];
    float z1 = z[nbase + plane];
    float z2 = z[nbase + 2 * plane];
    float z3 = z[nbase + 3 * plane];

    float y00 = 0.5f * (z0 + z1 + z2 + z3);
    float y01 = 0.5f * (z0 + z1 - z2 - z3);
    float y10 = 0.5f * (z0 - z1 + z2 - z3);
    float y11 = 0.5f * (z0 - z1 - z2 + z3);

    float* op = out + ((long)(b * Cc + c) * Hh + 2 * i) * Ww + 2 * j;
    float2* o0 = (float2*)op;
    float2* o1 = (float2*)(op + Ww);
    float2 s0 = *o0, s1 = *o1;
    s0.x += y00; s0.y += y01;
    s1.x += y10; s1.y += y11;
    *o0 = s0; *o1 = s1;
}

extern "C" void kernel_launch(void* const* d_in, const int* in_sizes, int n_in,
                              void* d_out, int out_size, void* d_ws, size_t ws_size,
                              hipStream_t stream) {
    const float* x        = (const float*)d_in[0];
    const float* conv_w   = (const float*)d_in[1];
    const float* conv_b   = (const float*)d_in[2];
    const float* base_w   = (const float*)d_in[3];
    const float* spline_w = (const float*)d_in[4];
    const float* scaler   = (const float*)d_in[5];
    float* out = (float*)d_out;
    float* wt  = (float*)d_ws;                    // 65536 x 128 fp32 = 32 MB

    // K1: Haar forward (2,097,152 threads)
    k_haar<<<(Bn * Cc * H2 * W2) / 256, 256, 0, stream>>>(x, wt);
    // K2: conv skip -> out (8,388,608 threads)
    k_conv<<<(Bn * Cc * Hh * Ww) / 256, 256, 0, stream>>>(x, conv_w, conv_b, out);
    // K3: KAN (in-place on wt)
    k_kan<<<(int)(NROWS / KROWS), 256, 0, stream>>>(wt, base_w, spline_w, scaler);
    // K4: inverse Haar += into out
    k_inv<<<(Bn * Cc * H2 * W2) / 256, 256, 0, stream>>>(wt, out);
}

// Round 2
// 234.055 us; speedup vs baseline: 5.6243x; 5.6243x over previous
//
#include <hip/hip_runtime.h>
#include <hip/hip_bf16.h>

using f32x4 = __attribute__((ext_vector_type(4))) float;
using s16x8 = __attribute__((ext_vector_type(8))) short;

// Problem dims (fixed by reference setup_inputs)
constexpr int Bn = 4, Cc = 32, Hh = 256, Ww = 256;
constexpr int H2 = 128, W2 = 128;
constexpr int NF = 128;                 // KAN feature dim (= W2)
constexpr long NROWS = (long)Bn * Cc * 4 * H2;  // 65536 KAN rows
constexpr int KTOT = 1152;              // 128 features x 9 (silu + 8 bases)
constexpr int KCH = 288;                // K-chunk: 32 features x 9
constexpr int LDA = 296;                // padded LDS row stride (shorts): 592B -> 2-way banks

// ---- bf16 round-to-nearest-even ----
__device__ __forceinline__ short f2bf(float f) {
    union { float f; unsigned u; } v; v.f = f;
    unsigned r = v.u + 0x7fffu + ((v.u >> 16) & 1u);
    return (short)(r >> 16);
}

// ---- cubic B-spline bases, matching reference Cox-de Boor (verified r1) ----
__device__ __forceinline__ float gridv(int t) {
    return (float)(t - 3) * 0.4f - 1.0f;
}

__device__ __forceinline__ void spline_bases(float x, float B[8]) {
    float b0[11];
#pragma unroll
    for (int t = 0; t < 11; ++t)
        b0[t] = (x >= gridv(t) && x < gridv(t + 1)) ? 1.0f : 0.0f;
    float b1[10];
#pragma unroll
    for (int t = 0; t < 10; ++t) {
        float d0 = gridv(t + 1) - gridv(t);
        float d1 = gridv(t + 2) - gridv(t + 1);
        b1[t] = (x - gridv(t)) * (1.0f / d0) * b0[t]
              + (gridv(t + 2) - x) * (1.0f / d1) * b0[t + 1];
    }
    float b2[9];
#pragma unroll
    for (int t = 0; t < 9; ++t) {
        float d0 = gridv(t + 2) - gridv(t);
        float d1 = gridv(t + 3) - gridv(t + 1);
        b2[t] = (x - gridv(t)) * (1.0f / d0) * b1[t]
              + (gridv(t + 3) - x) * (1.0f / d1) * b1[t + 1];
    }
#pragma unroll
    for (int t = 0; t < 8; ++t) {
        float d0 = gridv(t + 3) - gridv(t);
        float d1 = gridv(t + 4) - gridv(t + 1);
        B[t] = (x - gridv(t)) * (1.0f / d0) * b2[t]
             + (gridv(t + 4) - x) * (1.0f / d1) * b2[t + 1];
    }
}

// ---- K1: Haar forward -> wt rows n=((b*C+c)*4+k)*H2+i, features j ----
__global__ __launch_bounds__(256) void k_haar(const float* __restrict__ x,
                                              float* __restrict__ wt) {
    int idx = blockIdx.x * 256 + threadIdx.x;
    int j = idx & 127;
    int tmp = idx >> 7;
    int i = tmp & 127; tmp >>= 7;
    int c = tmp & 31;  int b = tmp >> 5;

    const float* base = x + (((long)(b * Cc + c) * Hh + 2 * i) * Ww);
    float2 r0 = ((const float2*)base)[j];
    float2 r1 = ((const float2*)(base + Ww))[j];
    float a = r0.x, bb = r0.y, cc = r1.x, dd = r1.y;

    float k0 = 0.5f * (a + bb + cc + dd);
    float k1 = 0.5f * (a + bb - cc - dd);
    float k2 = 0.5f * (a - bb + cc - dd);
    float k3 = 0.5f * (a - bb - cc + dd);

    long plane = (long)H2 * W2;
    long nbase = (((long)(b * Cc + c) * 4) * H2 + i) * (long)W2 + j;
    wt[nbase]             = k0;
    wt[nbase + plane]     = k1;
    wt[nbase + 2 * plane] = k2;
    wt[nbase + 3 * plane] = k3;
}

// ---- KW: fused bf16 weight matrix B[o][k], k = jg*288 + g*32 + jl ----
__global__ __launch_bounds__(256) void k_wbuild(const float* __restrict__ base_w,
                                                const float* __restrict__ spline_w,
                                                const float* __restrict__ scaler,
                                                short* __restrict__ Bg) {
    int idx = blockIdx.x * 256 + threadIdx.x;   // 128*1152 = 294912... grid=576 -> 147456
    int o = idx / KTOT;
    int k = idx - o * KTOT;
    int jg = k / KCH; int rem = k - jg * KCH;
    int g = rem >> 5; int jl = rem & 31;
    int j = jg * 32 + jl;
    float v = (g == 0) ? base_w[o * NF + j]
                       : spline_w[(long)(o * NF + j) * 8 + (g - 1)] * scaler[o * NF + j];
    Bg[idx] = f2bf(v);
}

// ---- K3: fused expand + MFMA GEMM, in-place z over wt ----
__global__ __launch_bounds__(256) void k_fused(float* __restrict__ wtz,
                                               const short* __restrict__ Bg) {
    __shared__ short A_lds[128 * LDA];          // 75776 B -> 2 blocks/CU
    const int t = threadIdx.x;
    const int lane = t & 63;
    const int wid = t >> 6;
    const int wm = wid >> 1, wn = wid & 1;      // 2x2 waves, 64x64 each
    const long n0 = (long)blockIdx.x * 128;

    f32x4 acc[4][4];
#pragma unroll
    for (int mi = 0; mi < 4; ++mi)
#pragma unroll
        for (int ni = 0; ni < 4; ++ni)
            acc[mi][ni] = (f32x4){0.f, 0.f, 0.f, 0.f};

    const int xrow = t >> 1;                    // 0..127
    const int jl0 = (t & 1) * 16;               // 0 or 16

    for (int jg = 0; jg < 4; ++jg) {
        __syncthreads();                        // A_lds safe to overwrite
        const float* xp = &wtz[(n0 + xrow) * NF + jg * 32 + jl0];
#pragma unroll
        for (int h = 0; h < 2; ++h) {
            f32x4 v0 = *(const f32x4*)(xp + h * 8);
            f32x4 v1 = *(const f32x4*)(xp + h * 8 + 4);
            float xv[8];
#pragma unroll
            for (int q = 0; q < 4; ++q) { xv[q] = v0[q]; xv[4 + q] = v1[q]; }
            float arr[72];                      // [g 0..8][q 0..7], fully unrolled
#pragma unroll
            for (int q = 0; q < 8; ++q) {
                float xx = xv[q];
                arr[q] = xx / (1.0f + expf(-xx));   // silu -> g=0
                float Bv[8];
                spline_bases(xx, Bv);
#pragma unroll
                for (int g = 0; g < 8; ++g) arr[(g + 1) * 8 + q] = Bv[g];
            }
#pragma unroll
            for (int g = 0; g < 9; ++g) {
                s16x8 pk;
#pragma unroll
                for (int q = 0; q < 8; ++q) pk[q] = f2bf(arr[g * 8 + q]);
                *(s16x8*)&A_lds[xrow * LDA + g * 32 + jl0 + h * 8] = pk;
            }
        }
        __syncthreads();
        // 9 MFMA K-steps of 32 over this 288-wide chunk
#pragma unroll
        for (int ks = 0; ks < 9; ++ks) {
            s16x8 af[4], bfr[4];
#pragma unroll
            for (int mi = 0; mi < 4; ++mi)
                af[mi] = *(const s16x8*)&A_lds[(wm * 64 + mi * 16 + (lane & 15)) * LDA
                                               + ks * 32 + (lane >> 4) * 8];
#pragma unroll
            for (int ni = 0; ni < 4; ++ni)
                bfr[ni] = *(const s16x8*)&Bg[(long)(wn * 64 + ni * 16 + (lane & 15)) * KTOT
                                             + jg * KCH + ks * 32 + (lane >> 4) * 8];
#pragma unroll
            for (int mi = 0; mi < 4; ++mi)
#pragma unroll
                for (int ni = 0; ni < 4; ++ni)
                    acc[mi][ni] = __builtin_amdgcn_mfma_f32_16x16x32_bf16(
                        af[mi], bfr[ni], acc[mi][ni], 0, 0, 0);
        }
    }
    // epilogue: z overwrites wt (own rows only; all reads done)
#pragma unroll
    for (int mi = 0; mi < 4; ++mi)
#pragma unroll
        for (int ni = 0; ni < 4; ++ni)
#pragma unroll
            for (int r = 0; r < 4; ++r) {
                int row = wm * 64 + mi * 16 + (lane >> 4) * 4 + r;
                int col = wn * 64 + ni * 16 + (lane & 15);
                wtz[(n0 + row) * NF + col] = acc[mi][ni][r];
            }
}

// ---- K2: depthwise 5x5 conv + bias -> d_out (skip) ----
__global__ __launch_bounds__(256) void k_conv(const float* __restrict__ x,
                                              const float* __restrict__ w,
                                              const float* __restrict__ bias,
                                              float* __restrict__ out) {
    int idx = blockIdx.x * 256 + threadIdx.x;
    int xc = idx & 255;
    int tmp = idx >> 8;
    int y = tmp & 255; tmp >>= 8;
    int c = tmp & 31;  int b = tmp >> 5;

    const float* xp = x + (long)(b * Cc + c) * Hh * Ww;
    const float* wp = w + c * 25;
    float acc = bias[c];
#pragma unroll
    for (int ky = 0; ky < 5; ++ky) {
        int yy = y + ky - 2;
        if (yy < 0 || yy >= Hh) continue;
#pragma unroll
        for (int kx = 0; kx < 5; ++kx) {
            int xx = xc + kx - 2;
            if (xx < 0 || xx >= Ww) continue;
            acc += xp[yy * Ww + xx] * wp[ky * 5 + kx];
        }
    }
    out[idx] = acc;
}

// ---- K4: inverse Haar, add into d_out (which holds skip) ----
__global__ __launch_bounds__(256) void k_inv(const float* __restrict__ z,
                                             float* __restrict__ out) {
    int idx = blockIdx.x * 256 + threadIdx.x;
    int j = idx & 127;
    int tmp = idx >> 7;
    int i = tmp & 127; tmp >>= 7;
    int c = tmp & 31;  int b = tmp >> 5;

    long plane = (long)H2 * W2;
    long nbase = (((long)(b * Cc + c) * 4) * H2 + i) * (long)W2 + j;
    float z0 = z[nbase];
    float z1 = z[nbase + plane];
    float z2 = z[nbase + 2 * plane];
    float z3 = z[nbase + 3 * plane];

    float y00 = 0.5f * (z0 + z1 + z2 + z3);
    float y01 = 0.5f * (z0 + z1 - z2 - z3);
    float y10 = 0.5f * (z0 - z1 + z2 - z3);
    float y11 = 0.5f * (z0 - z1 - z2 + z3);

    float* op = out + ((long)(b * Cc + c) * Hh + 2 * i) * Ww + 2 * j;
    float2* o0 = (float2*)op;
    float2* o1 = (float2*)(op + Ww);
    float2 s0 = *o0, s1 = *o1;
    s0.x += y00; s0.y += y01;
    s1.x += y10; s1.y += y11;
    *o0 = s0; *o1 = s1;
}

extern "C" void kernel_launch(void* const* d_in, const int* in_sizes, int n_in,
                              void* d_out, int out_size, void* d_ws, size_t ws_size,
                              hipStream_t stream) {
    const float* x        = (const float*)d_in[0];
    const float* conv_w   = (const float*)d_in[1];
    const float* conv_b   = (const float*)d_in[2];
    const float* base_w   = (const float*)d_in[3];
    const float* spline_w = (const float*)d_in[4];
    const float* scaler   = (const float*)d_in[5];
    float* out = (float*)d_out;
    float* wt  = (float*)d_ws;              // 65536 x 128 fp32 = 32 MiB
    short* Bg  = (short*)d_out;             // 288 KB staged in d_out; conv overwrites later

    // 1) Haar forward
    k_haar<<<(Bn * Cc * H2 * W2) / 256, 256, 0, stream>>>(x, wt);
    // 2) fused bf16 weights into d_out scratch (conv hasn't written skip yet)
    k_wbuild<<<(NF * KTOT) / 256, 256, 0, stream>>>(base_w, spline_w, scaler, Bg);
    // 3) fused expand+MFMA KAN, z in-place over wt
    k_fused<<<(int)(NROWS / 128), 256, 0, stream>>>(wt, Bg);
    // 4) conv skip -> out (overwrites Bg region; sequential on stream, safe)
    k_conv<<<(Bn * Cc * Hh * Ww) / 256, 256, 0, stream>>>(x, conv_w, conv_b, out);
    // 5) inverse Haar += into out
    k_inv<<<(Bn * Cc * H2 * W2) / 256, 256, 0, stream>>>(wt, out);
}

// Round 3
// 136.861 us; speedup vs baseline: 9.6185x; 1.7102x over previous
//
#include <hip/hip_runtime.h>
#include <hip/hip_bf16.h>

using f32x4 = __attribute__((ext_vector_type(4))) float;
using s16x8 = __attribute__((ext_vector_type(8))) short;

// Problem dims (fixed by reference setup_inputs)
constexpr int Bn = 4, Cc = 32, Hh = 256, Ww = 256;
constexpr int H2 = 128, W2 = 128;
constexpr int NF = 128;                 // KAN feature dim (= W2)
constexpr long NROWS = (long)Bn * Cc * 4 * H2;  // 65536 KAN rows
constexpr int KTOT = 1152;              // 128 features x 9 (silu + 8 bases)
constexpr int KCH = 288;                // K-chunk: 32 features x 9
constexpr int LDA = 296;                // padded LDS row stride (shorts)

// ---- bf16 round-to-nearest-even ----
__device__ __forceinline__ short f2bf(float f) {
    union { float f; unsigned u; } v; v.f = f;
    unsigned r = v.u + 0x7fffu + ((v.u >> 16) & 1u);
    return (short)(r >> 16);
}

// ---- cubic B-spline bases, matching reference Cox-de Boor (verified r1/r2) ----
__device__ __forceinline__ float gridv(int t) {
    return (float)(t - 3) * 0.4f - 1.0f;
}

__device__ __forceinline__ void spline_bases(float x, float B[8]) {
    float b0[11];
#pragma unroll
    for (int t = 0; t < 11; ++t)
        b0[t] = (x >= gridv(t) && x < gridv(t + 1)) ? 1.0f : 0.0f;
    float b1[10];
#pragma unroll
    for (int t = 0; t < 10; ++t) {
        float d0 = gridv(t + 1) - gridv(t);
        float d1 = gridv(t + 2) - gridv(t + 1);
        b1[t] = (x - gridv(t)) * (1.0f / d0) * b0[t]
              + (gridv(t + 2) - x) * (1.0f / d1) * b0[t + 1];
    }
    float b2[9];
#pragma unroll
    for (int t = 0; t < 9; ++t) {
        float d0 = gridv(t + 2) - gridv(t);
        float d1 = gridv(t + 3) - gridv(t + 1);
        b2[t] = (x - gridv(t)) * (1.0f / d0) * b1[t]
              + (gridv(t + 3) - x) * (1.0f / d1) * b1[t + 1];
    }
#pragma unroll
    for (int t = 0; t < 8; ++t) {
        float d0 = gridv(t + 3) - gridv(t);
        float d1 = gridv(t + 4) - gridv(t + 1);
        B[t] = (x - gridv(t)) * (1.0f / d0) * b2[t]
             + (gridv(t + 4) - x) * (1.0f / d1) * b2[t + 1];
    }
}

// ---- KW: fused bf16 weight matrix Bg[o][k], k = jg*288 + g*32 + jl ----
__global__ __launch_bounds__(256) void k_wbuild(const float* __restrict__ base_w,
                                                const float* __restrict__ spline_w,
                                                const float* __restrict__ scaler,
                                                short* __restrict__ Bg) {
    int idx = blockIdx.x * 256 + threadIdx.x;
    int o = idx / KTOT;
    int k = idx - o * KTOT;
    int jg = k / KCH; int rem = k - jg * KCH;
    int g = rem >> 5; int jl = rem & 31;
    int j = jg * 32 + jl;
    float v = (g == 0) ? base_w[o * NF + j]
                       : spline_w[(long)(o * NF + j) * 8 + (g - 1)] * scaler[o * NF + j];
    Bg[idx] = f2bf(v);
}

// ---- K3: Haar-forward + expand + MFMA GEMM -> z (ws) ----
// block = one (b,c,k) wavelet plane: rows n0..n0+127 (i = 0..127)
__global__ __launch_bounds__(256) void k_fused(const float* __restrict__ x,
                                               float* __restrict__ z,
                                               const short* __restrict__ Bg) {
    __shared__ short A_lds[128 * LDA];          // 75776 B
    const int t = threadIdx.x;
    const int lane = t & 63;
    const int wid = t >> 6;
    const int wm = wid >> 1, wn = wid & 1;      // 2x2 waves, 64x64 each
    const int blk = blockIdx.x;                 // ((b*32+c)*4 + k)
    const int kcomp = blk & 3;
    const int plane = blk >> 2;                 // b*32+c
    const long n0 = (long)blk * 128;
    const float* xp0 = x + (long)plane * Hh * Ww;

    // Haar signs: val = 0.5*(a + sB*b + sC*c + sD*d)
    const float sB = (kcomp & 2) ? -1.f : 1.f;
    const float sC = (kcomp & 1) ? -1.f : 1.f;
    const float sD = sB * sC;

    f32x4 acc[4][4];
#pragma unroll
    for (int mi = 0; mi < 4; ++mi)
#pragma unroll
        for (int ni = 0; ni < 4; ++ni)
            acc[mi][ni] = (f32x4){0.f, 0.f, 0.f, 0.f};

    const int xrow = t >> 1;                    // i = 0..127
    const int jl0 = (t & 1) * 16;               // 0 or 16

    for (int jg = 0; jg < 4; ++jg) {
        __syncthreads();                        // A_lds safe to overwrite
#pragma unroll
        for (int h = 0; h < 2; ++h) {
            int j0 = jg * 32 + jl0 + h * 8;     // first of 8 features
            const float* r0 = xp0 + (long)(2 * xrow) * Ww + 2 * j0;
            const float* r1 = r0 + Ww;
            float va[16], vb[16];
#pragma unroll
            for (int q4 = 0; q4 < 4; ++q4) {
                *(f32x4*)&va[q4 * 4] = *(const f32x4*)(r0 + q4 * 4);
                *(f32x4*)&vb[q4 * 4] = *(const f32x4*)(r1 + q4 * 4);
            }
            float arr[72];                      // [g 0..8][q 0..7]
#pragma unroll
            for (int q = 0; q < 8; ++q) {
                float xx = 0.5f * (va[2 * q] + sB * va[2 * q + 1]
                                 + sC * vb[2 * q] + sD * vb[2 * q + 1]);
                float e = __builtin_amdgcn_exp2f(-1.442695040889f * xx);
                arr[q] = xx * __builtin_amdgcn_rcpf(1.0f + e);   // silu
                float Bv[8];
                spline_bases(xx, Bv);
#pragma unroll
                for (int g = 0; g < 8; ++g) arr[(g + 1) * 8 + q] = Bv[g];
            }
#pragma unroll
            for (int g = 0; g < 9; ++g) {
                s16x8 pk;
#pragma unroll
                for (int q = 0; q < 8; ++q) pk[q] = f2bf(arr[g * 8 + q]);
                *(s16x8*)&A_lds[xrow * LDA + g * 32 + jl0 + h * 8] = pk;
            }
        }
        __syncthreads();
#pragma unroll
        for (int ks = 0; ks < 9; ++ks) {
            s16x8 af[4], bfr[4];
#pragma unroll
            for (int mi = 0; mi < 4; ++mi)
                af[mi] = *(const s16x8*)&A_lds[(wm * 64 + mi * 16 + (lane & 15)) * LDA
                                               + ks * 32 + (lane >> 4) * 8];
#pragma unroll
            for (int ni = 0; ni < 4; ++ni)
                bfr[ni] = *(const s16x8*)&Bg[(long)(wn * 64 + ni * 16 + (lane & 15)) * KTOT
                                             + jg * KCH + ks * 32 + (lane >> 4) * 8];
#pragma unroll
            for (int mi = 0; mi < 4; ++mi)
#pragma unroll
                for (int ni = 0; ni < 4; ++ni)
                    acc[mi][ni] = __builtin_amdgcn_mfma_f32_16x16x32_bf16(
                        af[mi], bfr[ni], acc[mi][ni], 0, 0, 0);
        }
    }
#pragma unroll
    for (int mi = 0; mi < 4; ++mi)
#pragma unroll
        for (int ni = 0; ni < 4; ++ni)
#pragma unroll
            for (int r = 0; r < 4; ++r) {
                int row = wm * 64 + mi * 16 + (lane >> 4) * 4 + r;
                int col = wn * 64 + ni * 16 + (lane & 15);
                z[(n0 + row) * NF + col] = acc[mi][ni][r];
            }
}

// ---- K4: depthwise 5x5 conv + bias + inverse Haar -> out (final) ----
__global__ __launch_bounds__(256) void k_invconv(const float* __restrict__ x,
                                                 const float* __restrict__ cw,
                                                 const float* __restrict__ cb,
                                                 const float* __restrict__ z,
                                                 float* __restrict__ out) {
    __shared__ float sx[68][70];                // 19040 B, padded stride
    const int t = threadIdx.x;
    const int blk = blockIdx.x;
    const int tile = blk & 15;                  // 4x4 tiles of 64x64
    const int plane = blk >> 4;                 // b*32+c
    const int ty = tile >> 2, tx = tile & 3;
    const int c = plane & 31;
    const int Y0 = ty * 64, X0 = tx * 64;
    const float* xp = x + (long)plane * Hh * Ww;

    // stage 68x68 x-tile with halo (zero-padded at plane edges)
    for (int idx = t; idx < 68 * 68; idx += 256) {
        int r = idx / 68, cc2 = idx - r * 68;
        int yy = Y0 - 2 + r, xx = X0 - 2 + cc2;
        float v = 0.f;
        if (yy >= 0 && yy < Hh && xx >= 0 && xx < Ww) v = xp[(long)yy * Ww + xx];
        sx[r][cc2] = v;
    }
    float w[25];
#pragma unroll
    for (int q = 0; q < 25; ++q) w[q] = cw[c * 25 + q];
    const float bias = cb[c];
    __syncthreads();

    const long zbase = (long)plane * 4 * H2 * W2;
    const long zplane = (long)H2 * W2;
#pragma unroll
    for (int p = 0; p < 4; ++p) {
        int q = t + p * 256;                    // quad id in 32x32
        int qy = q >> 5, qx = q & 31;
        int i = (Y0 >> 1) + qy, j = (X0 >> 1) + qx;
        long zi = zbase + (long)i * W2 + j;
        float z0 = z[zi];
        float z1 = z[zi + zplane];
        float z2 = z[zi + 2 * zplane];
        float z3 = z[zi + 3 * zplane];
        float y00 = 0.5f * (z0 + z1 + z2 + z3);
        float y01 = 0.5f * (z0 + z1 - z2 - z3);
        float y10 = 0.5f * (z0 - z1 + z2 - z3);
        float y11 = 0.5f * (z0 - z1 - z2 + z3);

        float vals[6][6];
#pragma unroll
        for (int r = 0; r < 6; ++r)
#pragma unroll
            for (int c2 = 0; c2 < 3; ++c2) {
                float2 vv = *(const float2*)&sx[2 * qy + r][2 * qx + 2 * c2];
                vals[r][2 * c2] = vv.x; vals[r][2 * c2 + 1] = vv.y;
            }
        float a00 = bias, a01 = bias, a10 = bias, a11 = bias;
#pragma unroll
        for (int ky = 0; ky < 5; ++ky)
#pragma unroll
            for (int kx = 0; kx < 5; ++kx) {
                float wv = w[ky * 5 + kx];
                a00 += wv * vals[ky][kx];
                a01 += wv * vals[ky][kx + 1];
                a10 += wv * vals[ky + 1][kx];
                a11 += wv * vals[ky + 1][kx + 1];
            }
        float* op = out + (long)plane * Hh * Ww + (long)(Y0 + 2 * qy) * Ww + X0 + 2 * qx;
        *(float2*)op = make_float2(a00 + y00, a01 + y01);
        *(float2*)(op + Ww) = make_float2(a10 + y10, a11 + y11);
    }
}

extern "C" void kernel_launch(void* const* d_in, const int* in_sizes, int n_in,
                              void* d_out, int out_size, void* d_ws, size_t ws_size,
                              hipStream_t stream) {
    const float* x        = (const float*)d_in[0];
    const float* conv_w   = (const float*)d_in[1];
    const float* conv_b   = (const float*)d_in[2];
    const float* base_w   = (const float*)d_in[3];
    const float* spline_w = (const float*)d_in[4];
    const float* scaler   = (const float*)d_in[5];
    float* out = (float*)d_out;
    float* z   = (float*)d_ws;              // 65536 x 128 fp32 = 32 MiB
    short* Bg  = (short*)d_out;             // 288 KB staged in d_out (overwritten by k_invconv)

    // 1) fused bf16 weights into d_out scratch
    k_wbuild<<<(NF * KTOT) / 256, 256, 0, stream>>>(base_w, spline_w, scaler, Bg);
    // 2) Haar + expand + MFMA KAN -> z
    k_fused<<<(int)(NROWS / 128), 256, 0, stream>>>(x, z, Bg);
    // 3) conv + inverse Haar -> out (fully overwrites d_out incl. Bg region)
    k_invconv<<<Bn * Cc * 16, 256, 0, stream>>>(x, conv_w, conv_b, z, out);
}

// Round 4
// 101.603 us; speedup vs baseline: 12.9564x; 1.3470x over previous
//
#include <hip/hip_runtime.h>
#include <hip/hip_bf16.h>

using f32x4 = __attribute__((ext_vector_type(4))) float;
using s16x8 = __attribute__((ext_vector_type(8))) short;
using s16x4 = __attribute__((ext_vector_type(4))) short;

// Problem dims (fixed by reference setup_inputs)
constexpr int Bn = 4, Cc = 32, Hh = 256, Ww = 256;
constexpr int H2 = 128, W2 = 128;
constexpr int NF = 128;                 // KAN feature dim (= W2)
constexpr long NROWS = (long)Bn * Cc * 4 * H2;  // 65536 KAN rows
constexpr int KTOT = 1152;              // 128 features x 9 (silu + 8 bases)
constexpr int KCH = 288;                // K-chunk: 32 features x 9
constexpr int LDA = 296;                // padded LDS row stride (shorts)

// ---- bf16 round-to-nearest-even ----
__device__ __forceinline__ short f2bf(float f) {
    union { float f; unsigned u; } v; v.f = f;
    unsigned r = v.u + 0x7fffu + ((v.u >> 16) & 1u);
    return (short)(r >> 16);
}

// ---- KW: fused bf16 weight matrix Bg[o][k], k = jg*288 + g*32 + jl ----
__global__ __launch_bounds__(256) void k_wbuild(const float* __restrict__ base_w,
                                                const float* __restrict__ spline_w,
                                                const float* __restrict__ scaler,
                                                short* __restrict__ Bg) {
    int idx = blockIdx.x * 256 + threadIdx.x;
    int o = idx / KTOT;
    int k = idx - o * KTOT;
    int jg = k / KCH; int rem = k - jg * KCH;
    int g = rem >> 5; int jl = rem & 31;
    int j = jg * 32 + jl;
    float v = (g == 0) ? base_w[o * NF + j]
                       : spline_w[(long)(o * NF + j) * 8 + (g - 1)] * scaler[o * NF + j];
    Bg[idx] = f2bf(v);
}

// ---- K3: Haar-forward + closed-form expand + MFMA GEMM -> z (ws) ----
// block = 64 rows of one (b,c,k) wavelet plane. 4 blocks/CU.
__global__ __launch_bounds__(256, 4) void k_fused(const float* __restrict__ x,
                                                  float* __restrict__ z,
                                                  const short* __restrict__ Bg) {
    __shared__ short A_lds[64 * LDA];           // 37,888 B -> 4 blocks/CU
    const int t = threadIdx.x;
    const int lane = t & 63;
    const int wv = t >> 6;                      // wave id: cols [wv*32, wv*32+32)
    const int blk = blockIdx.x;                 // (((plane)*4 + kcomp)*2 + ihalf)
    const int ihalf = blk & 1;
    const int kcomp = (blk >> 1) & 3;
    const int plane = blk >> 3;                 // b*32+c
    const long n0 = (long)blk * 64;
    const int i0 = ihalf * 64;
    const float* xp0 = x + (long)plane * Hh * Ww;

    // Haar signs: val = 0.5*(a + sB*b + sC*c + sD*d)
    const float sB = (kcomp & 2) ? -1.f : 1.f;
    const float sC = (kcomp & 1) ? -1.f : 1.f;
    const float sD = sB * sC;

    f32x4 acc[4][2];
#pragma unroll
    for (int mi = 0; mi < 4; ++mi)
#pragma unroll
        for (int ni = 0; ni < 2; ++ni)
            acc[mi][ni] = (f32x4){0.f, 0.f, 0.f, 0.f};

    const int r = t >> 2;                       // LDS row 0..63
    const int jl0 = (t & 3) * 8;                // feature sub-offset
    const int i = i0 + r;                       // plane row index

    for (int jg = 0; jg < 4; ++jg) {
        __syncthreads();                        // A_lds safe to overwrite
#pragma unroll
        for (int e = 0; e < 2; ++e) {
            const int j0 = jg * 32 + jl0 + e * 4;       // 4 features
            const float* rp = xp0 + (long)(2 * i) * Ww + 2 * j0;
            f32x4 a0 = *(const f32x4*)rp;
            f32x4 a1 = *(const f32x4*)(rp + 4);
            f32x4 b0 = *(const f32x4*)(rp + Ww);
            f32x4 b1 = *(const f32x4*)(rp + Ww + 4);
            float xx[4];
            xx[0] = 0.5f * (a0[0] + sB * a0[1] + sC * b0[0] + sD * b0[1]);
            xx[1] = 0.5f * (a0[2] + sB * a0[3] + sC * b0[2] + sD * b0[3]);
            xx[2] = 0.5f * (a1[0] + sB * a1[1] + sC * b1[0] + sD * b1[1]);
            xx[3] = 0.5f * (a1[2] + sB * a1[3] + sC * b1[2] + sD * b1[3]);
            float arr[9][4];
#pragma unroll
            for (int q = 0; q < 4; ++q) {
                float v = xx[q];
                float e2 = __builtin_amdgcn_exp2f(-1.442695040888963f * v);
                arr[0][q] = v * __builtin_amdgcn_rcpf(1.0f + e2);   // silu
                // closed-form uniform cubic B-spline: cell + local coord
                float xs = __builtin_fmaf(v, 2.5f, 5.5f);           // (v+2.2)*2.5
                float cf = floorf(xs);
                float u = xs - cf;
                int ci = (int)cf;
                float u2 = u * u, u3 = u2 * u;
                float wA = u3 * (1.f / 6.f);                        // B[cell]
                float wB = (1.f + 3.f * u + 3.f * u2 - 3.f * u3) * (1.f / 6.f);
                float wC = (4.f - 6.f * u2 + 3.f * u3) * (1.f / 6.f);
                float um = 1.f - u;
                float wD = um * um * um * (1.f / 6.f);              // B[cell-3]
#pragma unroll
                for (int tt = 0; tt < 8; ++tt) {
                    int d = ci - tt;
                    float bv = (d == 0) ? wA : (d == 1) ? wB
                             : (d == 2) ? wC : (d == 3) ? wD : 0.f;
                    arr[1 + tt][q] = bv;
                }
            }
#pragma unroll
            for (int g = 0; g < 9; ++g) {
                s16x4 pk;
#pragma unroll
                for (int q = 0; q < 4; ++q) pk[q] = f2bf(arr[g][q]);
                *(s16x4*)&A_lds[r * LDA + g * 32 + jl0 + e * 4] = pk;
            }
        }
        __syncthreads();
        __builtin_amdgcn_s_setprio(1);
#pragma unroll
        for (int ks = 0; ks < 9; ++ks) {
            s16x8 af[4], bfr[2];
#pragma unroll
            for (int mi = 0; mi < 4; ++mi)
                af[mi] = *(const s16x8*)&A_lds[(mi * 16 + (lane & 15)) * LDA
                                               + ks * 32 + (lane >> 4) * 8];
#pragma unroll
            for (int ni = 0; ni < 2; ++ni)
                bfr[ni] = *(const s16x8*)&Bg[(long)(wv * 32 + ni * 16 + (lane & 15)) * KTOT
                                             + jg * KCH + ks * 32 + (lane >> 4) * 8];
#pragma unroll
            for (int mi = 0; mi < 4; ++mi)
#pragma unroll
                for (int ni = 0; ni < 2; ++ni)
                    acc[mi][ni] = __builtin_amdgcn_mfma_f32_16x16x32_bf16(
                        af[mi], bfr[ni], acc[mi][ni], 0, 0, 0);
        }
        __builtin_amdgcn_s_setprio(0);
    }
#pragma unroll
    for (int mi = 0; mi < 4; ++mi)
#pragma unroll
        for (int ni = 0; ni < 2; ++ni)
#pragma unroll
            for (int rr = 0; rr < 4; ++rr) {
                int row = mi * 16 + (lane >> 4) * 4 + rr;
                int col = wv * 32 + ni * 16 + (lane & 15);
                z[(n0 + row) * NF + col] = acc[mi][ni][rr];
            }
}

// ---- K4: depthwise 5x5 conv + bias + inverse Haar -> out (final) ----
__global__ __launch_bounds__(256) void k_invconv(const float* __restrict__ x,
                                                 const float* __restrict__ cw,
                                                 const float* __restrict__ cb,
                                                 const float* __restrict__ z,
                                                 float* __restrict__ out) {
    __shared__ float sx[68][70];                // 19040 B, padded stride
    const int t = threadIdx.x;
    const int blk = blockIdx.x;
    const int tile = blk & 15;                  // 4x4 tiles of 64x64
    const int plane = blk >> 4;                 // b*32+c
    const int ty = tile >> 2, tx = tile & 3;
    const int c = plane & 31;
    const int Y0 = ty * 64, X0 = tx * 64;
    const float* xp = x + (long)plane * Hh * Ww;

    // stage 68x68 x-tile with halo (zero-padded at plane edges)
    for (int idx = t; idx < 68 * 68; idx += 256) {
        int rr = idx / 68, cc2 = idx - rr * 68;
        int yy = Y0 - 2 + rr, xxp = X0 - 2 + cc2;
        float v = 0.f;
        if (yy >= 0 && yy < Hh && xxp >= 0 && xxp < Ww) v = xp[(long)yy * Ww + xxp];
        sx[rr][cc2] = v;
    }
    float w[25];
#pragma unroll
    for (int q = 0; q < 25; ++q) w[q] = cw[c * 25 + q];
    const float bias = cb[c];
    __syncthreads();

    const long zbase = (long)plane * 4 * H2 * W2;
    const long zplane = (long)H2 * W2;
#pragma unroll
    for (int p = 0; p < 4; ++p) {
        int q = t + p * 256;                    // quad id in 32x32
        int qy = q >> 5, qx = q & 31;
        int i = (Y0 >> 1) + qy, j = (X0 >> 1) + qx;
        long zi = zbase + (long)i * W2 + j;
        float z0 = z[zi];
        float z1 = z[zi + zplane];
        float z2 = z[zi + 2 * zplane];
        float z3 = z[zi + 3 * zplane];
        float y00 = 0.5f * (z0 + z1 + z2 + z3);
        float y01 = 0.5f * (z0 + z1 - z2 - z3);
        float y10 = 0.5f * (z0 - z1 + z2 - z3);
        float y11 = 0.5f * (z0 - z1 - z2 + z3);

        float vals[6][6];
#pragma unroll
        for (int rr = 0; rr < 6; ++rr)
#pragma unroll
            for (int c2 = 0; c2 < 3; ++c2) {
                float2 vv = *(const float2*)&sx[2 * qy + rr][2 * qx + 2 * c2];
                vals[rr][2 * c2] = vv.x; vals[rr][2 * c2 + 1] = vv.y;
            }
        float a00 = bias, a01 = bias, a10 = bias, a11 = bias;
#pragma unroll
        for (int ky = 0; ky < 5; ++ky)
#pragma unroll
            for (int kx = 0; kx < 5; ++kx) {
                float wvv = w[ky * 5 + kx];
                a00 += wvv * vals[ky][kx];
                a01 += wvv * vals[ky][kx + 1];
                a10 += wvv * vals[ky + 1][kx];
                a11 += wvv * vals[ky + 1][kx + 1];
            }
        float* op = out + (long)plane * Hh * Ww + (long)(Y0 + 2 * qy) * Ww + X0 + 2 * qx;
        *(float2*)op = make_float2(a00 + y00, a01 + y01);
        *(float2*)(op + Ww) = make_float2(a10 + y10, a11 + y11);
    }
}

extern "C" void kernel_launch(void* const* d_in, const int* in_sizes, int n_in,
                              void* d_out, int out_size, void* d_ws, size_t ws_size,
                              hipStream_t stream) {
    const float* x        = (const float*)d_in[0];
    const float* conv_w   = (const float*)d_in[1];
    const float* conv_b   = (const float*)d_in[2];
    const float* base_w   = (const float*)d_in[3];
    const float* spline_w = (const float*)d_in[4];
    const float* scaler   = (const float*)d_in[5];
    float* out = (float*)d_out;
    float* z   = (float*)d_ws;              // 65536 x 128 fp32 = 32 MiB
    short* Bg  = (short*)d_out;             // 288 KB staged in d_out (overwritten by k_invconv)

    // 1) fused bf16 weights into d_out scratch
    k_wbuild<<<(NF * KTOT) / 256, 256, 0, stream>>>(base_w, spline_w, scaler, Bg);
    // 2) Haar + closed-form expand + MFMA KAN -> z (1024 blocks = 4/CU)
    k_fused<<<(int)(NROWS / 64), 256, 0, stream>>>(x, z, Bg);
    // 3) conv + inverse Haar -> out (fully overwrites d_out incl. Bg region)
    k_invconv<<<Bn * Cc * 16, 256, 0, stream>>>(x, conv_w, conv_b, z, out);
}

// Round 5
// 100.876 us; speedup vs baseline: 13.0497x; 1.0072x over previous
//
#include <hip/hip_runtime.h>
#include <hip/hip_bf16.h>

using f32x4 = __attribute__((ext_vector_type(4))) float;
using s16x8 = __attribute__((ext_vector_type(8))) short;

// Problem dims (fixed by reference setup_inputs)
constexpr int Bn = 4, Cc = 32, Hh = 256, Ww = 256;
constexpr int H2 = 128, W2 = 128;
constexpr int NF = 128;                 // KAN feature dim (= W2)
constexpr long NROWS = (long)Bn * Cc * 4 * H2;  // 65536 KAN rows
constexpr int KTOT = 1152;              // 128 features x 9 (silu + 8 bases)
constexpr int KCH = 288;                // K-chunk: 32 features x 9
constexpr int LDA = 296;                // padded LDS row stride (shorts)

// ---- bf16 round-to-nearest-even (host-side weight build only) ----
__device__ __forceinline__ short f2bf(float f) {
    union { float f; unsigned u; } v; v.f = f;
    unsigned r = v.u + 0x7fffu + ((v.u >> 16) & 1u);
    return (short)(r >> 16);
}

// hardware-converted bf16 pair -> packed u32 (v_cvt_pk_bf16_f32)
__device__ __forceinline__ unsigned pk_bf16(float a, float b) {
    union { __hip_bfloat162 h; unsigned u; } c;
    c.h.x = __float2bfloat16(a);
    c.h.y = __float2bfloat16(b);
    return c.u;
}

__device__ __forceinline__ float bsel(int d, float wA, float wB, float wC, float wD) {
    return (d == 0) ? wA : (d == 1) ? wB : (d == 2) ? wC : (d == 3) ? wD : 0.f;
}

// ---- KW: fused bf16 weight matrix Bg[o][k], k = jg*288 + g*32 + jl ----
__global__ __launch_bounds__(256) void k_wbuild(const float* __restrict__ base_w,
                                                const float* __restrict__ spline_w,
                                                const float* __restrict__ scaler,
                                                short* __restrict__ Bg) {
    int idx = blockIdx.x * 256 + threadIdx.x;
    int o = idx / KTOT;
    int k = idx - o * KTOT;
    int jg = k / KCH; int rem = k - jg * KCH;
    int g = rem >> 5; int jl = rem & 31;
    int j = jg * 32 + jl;
    float v = (g == 0) ? base_w[o * NF + j]
                       : spline_w[(long)(o * NF + j) * 8 + (g - 1)] * scaler[o * NF + j];
    Bg[idx] = f2bf(v);
}

// ---- K3: Haar butterfly (all 4 kcomp) + expand + MFMA GEMM -> z ----
// block = 16 i-rows x 4 kcomp = 64 KAN rows of one plane. 4 blocks/CU.
__global__ __launch_bounds__(256, 4) void k_fused(const float* __restrict__ x,
                                                  float* __restrict__ z,
                                                  const short* __restrict__ Bg) {
    __shared__ short A_lds[64 * LDA];           // 37,888 B -> 4 blocks/CU
    const int t = threadIdx.x;
    const int lane = t & 63;
    const int wv = t >> 6;                      // wave id: cols [wv*32, wv*32+32)
    const int blk = blockIdx.x;
    const int plane = blk >> 3;                 // b*32+c
    const int ic = blk & 7;
    const int i0 = ic << 4;                     // 16 i-rows per block
    const float* xp0 = x + (long)plane * Hh * Ww;

    const int il = t >> 4;                      // 0..15 (i_local)
    const int fg = t & 15;                      // 0..15 (feature pair group)

    // preload ALL x data for this thread: rows 2i, 2i+1; 4 chunks of 4 floats
    const float* rowp = xp0 + (long)(2 * (i0 + il)) * Ww + fg * 4;
    f32x4 xa[4], xb[4];
#pragma unroll
    for (int jg = 0; jg < 4; ++jg) {
        xa[jg] = *(const f32x4*)(rowp + jg * 64);
        xb[jg] = *(const f32x4*)(rowp + jg * 64 + Ww);
    }

    f32x4 acc[4][2];
#pragma unroll
    for (int mi = 0; mi < 4; ++mi)
#pragma unroll
        for (int ni = 0; ni < 2; ++ni)
            acc[mi][ni] = (f32x4){0.f, 0.f, 0.f, 0.f};

    for (int jg = 0; jg < 4; ++jg) {
        __syncthreads();                        // A_lds safe to overwrite
        // Haar butterfly: two feature-quads -> 4 kcomp x 2 features
        f32x4 A0 = xa[jg], B0 = xb[jg];
        float s01a = A0[0] + A0[1], d01a = A0[0] - A0[1];
        float s23a = B0[0] + B0[1], d23a = B0[0] - B0[1];
        float s01b = A0[2] + A0[3], d01b = A0[2] - A0[3];
        float s23b = B0[2] + B0[3], d23b = B0[2] - B0[3];
        float vkf[4][2];
        vkf[0][0] = 0.5f * (s01a + s23a); vkf[1][0] = 0.5f * (s01a - s23a);
        vkf[2][0] = 0.5f * (d01a + d23a); vkf[3][0] = 0.5f * (d01a - d23a);
        vkf[0][1] = 0.5f * (s01b + s23b); vkf[1][1] = 0.5f * (s01b - s23b);
        vkf[2][1] = 0.5f * (d01b + d23b); vkf[3][1] = 0.5f * (d01b - d23b);

#pragma unroll
        for (int k = 0; k < 4; ++k) {
            float sl[2], wA[2], wB[2], wC[2], wD[2]; int ci[2];
#pragma unroll
            for (int f = 0; f < 2; ++f) {
                float v = vkf[k][f];
                float e2 = __builtin_amdgcn_exp2f(-1.442695040888963f * v);
                sl[f] = v * __builtin_amdgcn_rcpf(1.0f + e2);       // silu
                float xs = __builtin_fmaf(v, 2.5f, 5.5f);           // (v+2.2)*2.5
                float cf = floorf(xs);
                float u = xs - cf;
                ci[f] = (int)cf;
                float u2 = u * u, u3 = u2 * u;
                wA[f] = u3 * (1.f / 6.f);                           // slot ci
                wB[f] = (1.f + 3.f * u + 3.f * u2 - 3.f * u3) * (1.f / 6.f);
                wC[f] = (4.f - 6.f * u2 + 3.f * u3) * (1.f / 6.f);
                float um = 1.f - u;
                wD[f] = um * um * um * (1.f / 6.f);                 // slot ci-3
            }
            unsigned* wp = (unsigned*)&A_lds[(k * 16 + il) * LDA + fg * 2];
            wp[0] = pk_bf16(sl[0], sl[1]);                          // g = 0 (stride 32 shorts = 16 u32)
#pragma unroll
            for (int tt = 0; tt < 8; ++tt) {
                float b0 = bsel(ci[0] - tt, wA[0], wB[0], wC[0], wD[0]);
                float b1 = bsel(ci[1] - tt, wA[1], wB[1], wC[1], wD[1]);
                wp[(1 + tt) * 16] = pk_bf16(b0, b1);
            }
        }
        __syncthreads();
        __builtin_amdgcn_s_setprio(1);
#pragma unroll
        for (int ks = 0; ks < 9; ++ks) {
            s16x8 af[4], bfr[2];
#pragma unroll
            for (int mi = 0; mi < 4; ++mi)
                af[mi] = *(const s16x8*)&A_lds[(mi * 16 + (lane & 15)) * LDA
                                               + ks * 32 + (lane >> 4) * 8];
#pragma unroll
            for (int ni = 0; ni < 2; ++ni)
                bfr[ni] = *(const s16x8*)&Bg[(long)(wv * 32 + ni * 16 + (lane & 15)) * KTOT
                                             + jg * KCH + ks * 32 + (lane >> 4) * 8];
#pragma unroll
            for (int mi = 0; mi < 4; ++mi)
#pragma unroll
                for (int ni = 0; ni < 2; ++ni)
                    acc[mi][ni] = __builtin_amdgcn_mfma_f32_16x16x32_bf16(
                        af[mi], bfr[ni], acc[mi][ni], 0, 0, 0);
        }
        __builtin_amdgcn_s_setprio(0);
    }
    // epilogue: local row = kcomp*16 + i_local, kcomp = mi
#pragma unroll
    for (int mi = 0; mi < 4; ++mi) {
        long nb = ((long)(plane * 4 + mi) * H2 + i0) * NF;
#pragma unroll
        for (int ni = 0; ni < 2; ++ni)
#pragma unroll
            for (int rr = 0; rr < 4; ++rr) {
                int ilr = (lane >> 4) * 4 + rr;
                int col = wv * 32 + ni * 16 + (lane & 15);
                z[nb + (long)ilr * NF + col] = acc[mi][ni][rr];
            }
    }
}

// ---- K4: depthwise 5x5 conv + bias + inverse Haar -> out (final) ----
__global__ __launch_bounds__(256) void k_invconv(const float* __restrict__ x,
                                                 const float* __restrict__ cw,
                                                 const float* __restrict__ cb,
                                                 const float* __restrict__ z,
                                                 float* __restrict__ out) {
    __shared__ float sx[68][70];                // 19040 B, padded stride
    const int t = threadIdx.x;
    const int blk = blockIdx.x;
    const int tile = blk & 15;                  // 4x4 tiles of 64x64
    const int plane = blk >> 4;                 // b*32+c
    const int ty = tile >> 2, tx = tile & 3;
    const int c = plane & 31;
    const int Y0 = ty * 64, X0 = tx * 64;
    const float* xp = x + (long)plane * Hh * Ww;

    for (int idx = t; idx < 68 * 68; idx += 256) {
        int rr = idx / 68, cc2 = idx - rr * 68;
        int yy = Y0 - 2 + rr, xxp = X0 - 2 + cc2;
        float v = 0.f;
        if (yy >= 0 && yy < Hh && xxp >= 0 && xxp < Ww) v = xp[(long)yy * Ww + xxp];
        sx[rr][cc2] = v;
    }
    float w[25];
#pragma unroll
    for (int q = 0; q < 25; ++q) w[q] = cw[c * 25 + q];
    const float bias = cb[c];
    __syncthreads();

    const long zbase = (long)plane * 4 * H2 * W2;
    const long zplane = (long)H2 * W2;
#pragma unroll
    for (int p = 0; p < 4; ++p) {
        int q = t + p * 256;                    // quad id in 32x32
        int qy = q >> 5, qx = q & 31;
        int i = (Y0 >> 1) + qy, j = (X0 >> 1) + qx;
        long zi = zbase + (long)i * W2 + j;
        float z0 = z[zi];
        float z1 = z[zi + zplane];
        float z2 = z[zi + 2 * zplane];
        float z3 = z[zi + 3 * zplane];
        float y00 = 0.5f * (z0 + z1 + z2 + z3);
        float y01 = 0.5f * (z0 + z1 - z2 - z3);
        float y10 = 0.5f * (z0 - z1 + z2 - z3);
        float y11 = 0.5f * (z0 - z1 - z2 + z3);

        float vals[6][6];
#pragma unroll
        for (int rr = 0; rr < 6; ++rr)
#pragma unroll
            for (int c2 = 0; c2 < 3; ++c2) {
                float2 vv = *(const float2*)&sx[2 * qy + rr][2 * qx + 2 * c2];
                vals[rr][2 * c2] = vv.x; vals[rr][2 * c2 + 1] = vv.y;
            }
        float a00 = bias, a01 = bias, a10 = bias, a11 = bias;
#pragma unroll
        for (int ky = 0; ky < 5; ++ky)
#pragma unroll
            for (int kx = 0; kx < 5; ++kx) {
                float wvv = w[ky * 5 + kx];
                a00 += wvv * vals[ky][kx];
                a01 += wvv * vals[ky][kx + 1];
                a10 += wvv * vals[ky + 1][kx];
                a11 += wvv * vals[ky + 1][kx + 1];
            }
        float* op = out + (long)plane * Hh * Ww + (long)(Y0 + 2 * qy) * Ww + X0 + 2 * qx;
        *(float2*)op = make_float2(a00 + y00, a01 + y01);
        *(float2*)(op + Ww) = make_float2(a10 + y10, a11 + y11);
    }
}

extern "C" void kernel_launch(void* const* d_in, const int* in_sizes, int n_in,
                              void* d_out, int out_size, void* d_ws, size_t ws_size,
                              hipStream_t stream) {
    const float* x        = (const float*)d_in[0];
    const float* conv_w   = (const float*)d_in[1];
    const float* conv_b   = (const float*)d_in[2];
    const float* base_w   = (const float*)d_in[3];
    const float* spline_w = (const float*)d_in[4];
    const float* scaler   = (const float*)d_in[5];
    float* out = (float*)d_out;
    float* z   = (float*)d_ws;              // 65536 x 128 fp32 = 32 MiB
    short* Bg  = (short*)d_out;             // 288 KB staged in d_out (overwritten by k_invconv)

    // 1) fused bf16 weights into d_out scratch
    k_wbuild<<<(NF * KTOT) / 256, 256, 0, stream>>>(base_w, spline_w, scaler, Bg);
    // 2) Haar butterfly + expand + MFMA KAN -> z (1024 blocks = 4/CU)
    k_fused<<<(int)(NROWS / 64), 256, 0, stream>>>(x, z, Bg);
    // 3) conv + inverse Haar -> out (fully overwrites d_out incl. Bg region)
    k_invconv<<<Bn * Cc * 16, 256, 0, stream>>>(x, conv_w, conv_b, z, out);
}

// Round 6
// 81.616 us; speedup vs baseline: 16.1292x; 1.2360x over previous
//
#include <hip/hip_runtime.h>
#include <hip/hip_bf16.h>

using f32x4 = __attribute__((ext_vector_type(4))) float;
using s16x8 = __attribute__((ext_vector_type(8))) short;
using u32x4 = __attribute__((ext_vector_type(4))) unsigned;

// Problem dims (fixed by reference setup_inputs)
constexpr int Bn = 4, Cc = 32, Hh = 256, Ww = 256;
constexpr int H2 = 128, W2 = 128;
constexpr int NF = 128;                 // KAN feature dim (= W2)
constexpr long NROWS = (long)Bn * Cc * 4 * H2;  // 65536 KAN rows
constexpr int KTOT = 1152;              // 128 features x 9 (silu + 8 bases)
constexpr int KCH = 288;                // K-chunk: 32 features x 9
constexpr int LDA = 296;                // padded LDS row stride (shorts)

// ---- bf16 round-to-nearest-even ----
__device__ __forceinline__ short f2bf(float f) {
    union { float f; unsigned u; } v; v.f = f;
    unsigned r = v.u + 0x7fffu + ((v.u >> 16) & 1u);
    return (short)(r >> 16);
}

// hardware bf16 pair pack (v_cvt_pk_bf16_f32)
__device__ __forceinline__ unsigned pk_bf16(float a, float b) {
    union { __hip_bfloat162 h; unsigned u; } c;
    c.h.x = __float2bfloat16(a);
    c.h.y = __float2bfloat16(b);
    return c.u;
}

// Place [wD,wC,wB,wA] (bf16-packed u64) at slot (ci-3) of an 8-slot 128-bit
// window; slots outside [0,7] dropped; ci outside [0,10] -> all zero.
__device__ __forceinline__ void window128(float wD, float wC, float wB, float wA,
                                          int ci, unsigned W[4]) {
    unsigned long long P = ((unsigned long long)pk_bf16(wB, wA) << 32)
                         | (unsigned long long)pk_bf16(wD, wC);
    int sh = ci * 16 - 48;
    unsigned long long sl = P << (sh & 63);
    unsigned long long sr = P >> ((-sh) & 63);
    unsigned long long lo = (sh < 0) ? sr : ((sh < 64) ? sl : 0ull);
    int shh = sh - 64;
    unsigned long long sl2 = P << (shh & 63);
    unsigned long long sr2 = P >> ((-shh) & 63);
    unsigned long long hi = (shh >= 0) ? sl2 : (((-shh) < 64) ? sr2 : 0ull);
    if ((unsigned)ci > 10u) { lo = 0ull; hi = 0ull; }
    W[0] = (unsigned)lo; W[1] = (unsigned)(lo >> 32);
    W[2] = (unsigned)hi; W[3] = (unsigned)(hi >> 32);
}

// ---- KW: fused bf16 weight matrix Bg[o][k], k = jg*288 + g*32 + jl ----
__global__ __launch_bounds__(256) void k_wbuild(const float* __restrict__ base_w,
                                                const float* __restrict__ spline_w,
                                                const float* __restrict__ scaler,
                                                short* __restrict__ Bg) {
    int idx = blockIdx.x * 256 + threadIdx.x;
    int o = idx / KTOT;
    int k = idx - o * KTOT;
    int jg = k / KCH; int rem = k - jg * KCH;
    int g = rem >> 5; int jl = rem & 31;
    int j = jg * 32 + jl;
    float v = (g == 0) ? base_w[o * NF + j]
                       : spline_w[(long)(o * NF + j) * 8 + (g - 1)] * scaler[o * NF + j];
    Bg[idx] = f2bf(v);
}

// ---- K3: Haar + funnel-shift expand + MFMA GEMM, software-pipelined ----
// block = 16 i-rows x 4 kcomp = 64 KAN rows of one plane. 4 blocks/CU.
__global__ __launch_bounds__(256, 4) void k_fused(const float* __restrict__ x,
                                                  float* __restrict__ z,
                                                  const short* __restrict__ Bg) {
    __shared__ short A_lds[64 * LDA];           // 37,888 B -> 4 blocks/CU
    const int t = threadIdx.x;
    const int lane = t & 63;
    const int wv = t >> 6;                      // wave id: cols [wv*32, wv*32+32)
    const int blk = blockIdx.x;
    const int plane = blk >> 3;                 // b*32+c
    const int i0 = (blk & 7) << 4;              // 16 i-rows per block
    const float* xp0 = x + (long)plane * Hh * Ww;

    // expansion ownership: thread -> LDS row r (kcomp,il) x 8 features (fb)
    const int r = t & 63;
    const int kcomp = r >> 4, il = r & 15;
    const int fb = t >> 6;                      // feature block 0..3 (8 features)
    const float sB = (kcomp & 2) ? -1.f : 1.f;
    const float sC = (kcomp & 1) ? -1.f : 1.f;
    const float sD = sB * sC;
    const float* xrow0 = xp0 + (long)(2 * (i0 + il)) * Ww;
    const float* xrow1 = xrow0 + Ww;

    f32x4 acc[4][2];
#pragma unroll
    for (int mi = 0; mi < 4; ++mi)
#pragma unroll
        for (int ni = 0; ni < 2; ++ni)
            acc[mi][ni] = (f32x4){0.f, 0.f, 0.f, 0.f};

    u32x4 stg[9];                               // staged A slots (36 u32)

    auto expand = [&](int jg) {
        const int cb = 2 * (jg * 32 + fb * 8);  // x column base
#pragma unroll
        for (int p = 0; p < 4; ++p) {           // feature pairs
            f32x4 r0 = *(const f32x4*)(xrow0 + cb + 4 * p);
            f32x4 r1 = *(const f32x4*)(xrow1 + cb + 4 * p);
            float sl2[2]; unsigned Wf[2][4];
#pragma unroll
            for (int e = 0; e < 2; ++e) {
                float a0 = r0[2 * e], a1 = r0[2 * e + 1];
                float b0 = r1[2 * e], b1 = r1[2 * e + 1];
                float v = 0.5f * (a0 + sB * a1 + sC * b0 + sD * b1);
                float ex = __builtin_amdgcn_exp2f(-1.442695040888963f * v);
                sl2[e] = v * __builtin_amdgcn_rcpf(1.0f + ex);      // silu
                float xs = __builtin_fmaf(v, 2.5f, 5.5f);           // (v+2.2)*2.5
                float cf = floorf(xs);
                float u = xs - cf;
                int ci = (int)cf;
                float u2 = u * u, u3 = u2 * u;
                float wA = u3 * (1.f / 6.f);
                float wB = (1.f + 3.f * u + 3.f * u2 - 3.f * u3) * (1.f / 6.f);
                float wC = (4.f - 6.f * u2 + 3.f * u3) * (1.f / 6.f);
                float um = 1.f - u;
                float wD = um * um * um * (1.f / 6.f);
                window128(wD, wC, wB, wA, ci, Wf[e]);
            }
            stg[0][p] = pk_bf16(sl2[0], sl2[1]);
#pragma unroll
            for (int g = 1; g <= 8; ++g) {
                int w = (g - 1) >> 1;
                unsigned sel = ((g - 1) & 1) ? 0x07060302u : 0x05040100u;
                // bytes 0-1 from feature-even (src1=lo), 2-3 from feature-odd
                stg[g][p] = __builtin_amdgcn_perm(Wf[1][w], Wf[0][w], sel);
            }
        }
    };

    expand(0);
    for (int jg = 0; jg < 4; ++jg) {
        __syncthreads();                        // previous MFMA done, LDS free
#pragma unroll
        for (int g = 0; g < 9; ++g)
            *(u32x4*)&A_lds[r * LDA + g * 32 + fb * 8] = stg[g];
        __syncthreads();                        // A ready
        __builtin_amdgcn_s_setprio(1);
#pragma unroll
        for (int ks = 0; ks < 9; ++ks) {
            s16x8 af[4], bfr[2];
#pragma unroll
            for (int mi = 0; mi < 4; ++mi)
                af[mi] = *(const s16x8*)&A_lds[(mi * 16 + (lane & 15)) * LDA
                                               + ks * 32 + (lane >> 4) * 8];
#pragma unroll
            for (int ni = 0; ni < 2; ++ni)
                bfr[ni] = *(const s16x8*)&Bg[(long)(wv * 32 + ni * 16 + (lane & 15)) * KTOT
                                             + jg * KCH + ks * 32 + (lane >> 4) * 8];
#pragma unroll
            for (int mi = 0; mi < 4; ++mi)
#pragma unroll
                for (int ni = 0; ni < 2; ++ni)
                    acc[mi][ni] = __builtin_amdgcn_mfma_f32_16x16x32_bf16(
                        af[mi], bfr[ni], acc[mi][ni], 0, 0, 0);
        }
        __builtin_amdgcn_s_setprio(0);
        if (jg < 3) expand(jg + 1);             // overlaps MFMA region above
    }
    // epilogue: local row = kcomp*16 + il, kcomp = mi
#pragma unroll
    for (int mi = 0; mi < 4; ++mi) {
        long nb = ((long)(plane * 4 + mi) * H2 + i0) * NF;
#pragma unroll
        for (int ni = 0; ni < 2; ++ni)
#pragma unroll
            for (int rr = 0; rr < 4; ++rr) {
                int ilr = (lane >> 4) * 4 + rr;
                int col = wv * 32 + ni * 16 + (lane & 15);
                z[nb + (long)ilr * NF + col] = acc[mi][ni][rr];
            }
    }
}

// ---- K4: depthwise 5x5 conv + bias + inverse Haar -> out (final) ----
__global__ __launch_bounds__(256) void k_invconv(const float* __restrict__ x,
                                                 const float* __restrict__ cw,
                                                 const float* __restrict__ cb,
                                                 const float* __restrict__ z,
                                                 float* __restrict__ out) {
    __shared__ float sx[68][70];                // 19040 B, padded stride
    const int t = threadIdx.x;
    const int blk = blockIdx.x;
    const int tile = blk & 15;                  // 4x4 tiles of 64x64
    const int plane = blk >> 4;                 // b*32+c
    const int ty = tile >> 2, tx = tile & 3;
    const int c = plane & 31;
    const int Y0 = ty * 64, X0 = tx * 64;
    const float* xp = x + (long)plane * Hh * Ww;

    for (int idx = t; idx < 68 * 68; idx += 256) {
        int rr = idx / 68, cc2 = idx - rr * 68;
        int yy = Y0 - 2 + rr, xxp = X0 - 2 + cc2;
        float v = 0.f;
        if (yy >= 0 && yy < Hh && xxp >= 0 && xxp < Ww) v = xp[(long)yy * Ww + xxp];
        sx[rr][cc2] = v;
    }
    float w[25];
#pragma unroll
    for (int q = 0; q < 25; ++q) w[q] = cw[c * 25 + q];
    const float bias = cb[c];
    __syncthreads();

    const long zbase = (long)plane * 4 * H2 * W2;
    const long zplane = (long)H2 * W2;
#pragma unroll
    for (int p = 0; p < 4; ++p) {
        int q = t + p * 256;                    // quad id in 32x32
        int qy = q >> 5, qx = q & 31;
        int i = (Y0 >> 1) + qy, j = (X0 >> 1) + qx;
        long zi = zbase + (long)i * W2 + j;
        float z0 = z[zi];
        float z1 = z[zi + zplane];
        float z2 = z[zi + 2 * zplane];
        float z3 = z[zi + 3 * zplane];
        float y00 = 0.5f * (z0 + z1 + z2 + z3);
        float y01 = 0.5f * (z0 + z1 - z2 - z3);
        float y10 = 0.5f * (z0 - z1 + z2 - z3);
        float y11 = 0.5f * (z0 - z1 - z2 + z3);

        float vals[6][6];
#pragma unroll
        for (int rr = 0; rr < 6; ++rr)
#pragma unroll
            for (int c2 = 0; c2 < 3; ++c2) {
                float2 vv = *(const float2*)&sx[2 * qy + rr][2 * qx + 2 * c2];
                vals[rr][2 * c2] = vv.x; vals[rr][2 * c2 + 1] = vv.y;
            }
        float a00 = bias, a01 = bias, a10 = bias, a11 = bias;
#pragma unroll
        for (int ky = 0; ky < 5; ++ky)
#pragma unroll
            for (int kx = 0; kx < 5; ++kx) {
                float wvv = w[ky * 5 + kx];
                a00 += wvv * vals[ky][kx];
                a01 += wvv * vals[ky][kx + 1];
                a10 += wvv * vals[ky + 1][kx];
                a11 += wvv * vals[ky + 1][kx + 1];
            }
        float* op = out + (long)plane * Hh * Ww + (long)(Y0 + 2 * qy) * Ww + X0 + 2 * qx;
        *(float2*)op = make_float2(a00 + y00, a01 + y01);
        *(float2*)(op + Ww) = make_float2(a10 + y10, a11 + y11);
    }
}

extern "C" void kernel_launch(void* const* d_in, const int* in_sizes, int n_in,
                              void* d_out, int out_size, void* d_ws, size_t ws_size,
                              hipStream_t stream) {
    const float* x        = (const float*)d_in[0];
    const float* conv_w   = (const float*)d_in[1];
    const float* conv_b   = (const float*)d_in[2];
    const float* base_w   = (const float*)d_in[3];
    const float* spline_w = (const float*)d_in[4];
    const float* scaler   = (const float*)d_in[5];
    float* out = (float*)d_out;
    float* z   = (float*)d_ws;              // 65536 x 128 fp32 = 32 MiB
    short* Bg  = (short*)d_out;             // 288 KB staged in d_out (overwritten by k_invconv)

    // 1) fused bf16 weights into d_out scratch
    k_wbuild<<<(NF * KTOT) / 256, 256, 0, stream>>>(base_w, spline_w, scaler, Bg);
    // 2) Haar + funnel expand + MFMA KAN -> z (1024 blocks = 4/CU)
    k_fused<<<(int)(NROWS / 64), 256, 0, stream>>>(x, z, Bg);
    // 3) conv + inverse Haar -> out (fully overwrites d_out incl. Bg region)
    k_invconv<<<Bn * Cc * 16, 256, 0, stream>>>(x, conv_w, conv_b, z, out);
}